// Round 1
// 530.338 us; speedup vs baseline: 1.1035x; 1.1035x over previous
//
#include <hip/hip_runtime.h>
#include <stdint.h>

#define B_DIM 8
#define T_DIM 1024
#define C_DIM 2048
#define M_DIM (B_DIM * T_DIM)   // 8192 rows = B*T
#define SEG   32                // segments for wkv scan
#define SEGL  (T_DIM / SEG)     // 32 steps per segment

typedef __bf16 bf16x8 __attribute__((ext_vector_type(8)));
typedef __bf16 bf16x4 __attribute__((ext_vector_type(4)));
typedef float  f32x4  __attribute__((ext_vector_type(4)));

// ---------------------------------------------------------------------------
// async global -> LDS, 16 bytes per lane (global_load_lds_dwordx4).
// LDS dest is wave-uniform base + lane*16 (m104/m108 semantics).
// ---------------------------------------------------------------------------
__device__ __forceinline__ void gld_lds16(const void* g, void* l) {
    __builtin_amdgcn_global_load_lds((__attribute__((address_space(1))) void*)g,
                                     (__attribute__((address_space(3))) void*)l,
                                     16, 0, 0);
}

// ---------------------------------------------------------------------------
// Downcast the 4 weight matrices fp32 -> bf16.  grid (C*C/1024, 4) x 256.
// ---------------------------------------------------------------------------
__global__ __launch_bounds__(256) void cast_w_kernel(
    const float* __restrict__ w0, const float* __restrict__ w1,
    const float* __restrict__ w2, const float* __restrict__ w3,
    __bf16* __restrict__ dst) {
    const float* srcs[4] = {w0, w1, w2, w3};
    const float* s = srcs[blockIdx.y];
    __bf16* d = dst + (size_t)blockIdx.y * (size_t)C_DIM * C_DIM;
    const size_t i = ((size_t)blockIdx.x * 256 + threadIdx.x) * 4;
    f32x4 v = *(const f32x4*)(s + i);
    bf16x4 o;
#pragma unroll
    for (int j = 0; j < 4; ++j) o[j] = (__bf16)v[j];
    *(bf16x4*)(d + i) = o;
}

// ---------------------------------------------------------------------------
// Time-shift mixing: xk/xv/xr = x*m + shift(x)*(1-m).  fp32 in, bf16 out.
// ---------------------------------------------------------------------------
__global__ __launch_bounds__(256) void mix4_kernel(
    const float* __restrict__ x,
    const float* __restrict__ mk, const float* __restrict__ mv,
    const float* __restrict__ mr,
    __bf16* __restrict__ xk, __bf16* __restrict__ xv, __bf16* __restrict__ xr) {
    const size_t idx = ((size_t)blockIdx.x * 256 + threadIdx.x) * 4;
    const int c = (int)(idx & (C_DIM - 1));
    const int t = (int)((idx >> 11) & (T_DIM - 1));   // C_DIM == 2^11

    f32x4 xc = *(const f32x4*)(x + idx);
    f32x4 sh = {0.f, 0.f, 0.f, 0.f};
    if (t != 0) sh = *(const f32x4*)(x + idx - C_DIM);
    f32x4 k4 = *(const f32x4*)(mk + c);
    f32x4 v4 = *(const f32x4*)(mv + c);
    f32x4 r4 = *(const f32x4*)(mr + c);

    bf16x4 ok, ov, orr;
#pragma unroll
    for (int j = 0; j < 4; ++j) {
        float xx = xc[j], ss = sh[j];
        ok[j]  = (__bf16)(xx * k4[j] + ss * (1.f - k4[j]));
        ov[j]  = (__bf16)(xx * v4[j] + ss * (1.f - v4[j]));
        orr[j] = (__bf16)(xx * r4[j] + ss * (1.f - r4[j]));
    }
    *(bf16x4*)(xk + idx) = ok;
    *(bf16x4*)(xv + idx) = ov;
    *(bf16x4*)(xr + idx) = orr;
}

// ---------------------------------------------------------------------------
// 256x256 bf16 GEMM, B^T input:  Cout[m][n] = sum_k A[m][k] * W[n][k]
// Deep-pipelined schedule (T2+T3+T4+T5 from the technique catalog):
//   - BK=32 K-tiles in a 4-deep LDS ring (4 x (16KB A + 16KB B) = 128 KiB).
//   - Stage stream leads compute by 3 tiles: tile t lives in buf[t&3]; while
//     computing tile t we stage tile t+3 into buf[(t+3)&3].  A buffer is
//     rewritten only 3 blocks after its last read (behind 2 vmcnt+barrier
//     pairs) -> race-free by construction, robust to compiler code motion.
//   - Per tile: 2 phases x 16 MFMA 16x16x32_bf16.  Phase1 stages A-halves,
//     phase2 stages B-halves (uniform per-wave issue order: A0,A1,B0,B1 =
//     4 vmem loads/tile/thread).  One s_waitcnt vmcnt(8) per tile (leaves
//     tiles t+2,t+3 = 8 loads in flight; NEVER drains to 0 in steady state),
//     placed BEFORE the barrier so all waves' staging is visible after it.
//   - Raw s_barrier (no implicit vmcnt drain), s_setprio(1) around MFMA
//     clusters; acc[0..3]/acc[4..7] alternate between phases so consecutive
//     MFMA clusters have no RAW dependence.
//   - LDS swizzle: 2-row 128B units, slot8 = (q + 4*(row&1)) ^ (unit&7).
//     Every 16-lane b128 read batch hits each bank exactly 2x (free, m136).
//     Inverse swizzle applied on the GLOBAL source of global_load_lds
//     (both-sides-or-neither); LDS writes stay linear (DMA constraint).
//   - grid = 32x8 = 256 blocks = exactly 1/CU; XCD-swizzle gives each XCD
//     one 1MB W-panel (L2-resident, reused by its 32 M-blocks).
// ---------------------------------------------------------------------------
#define VMCNT(N) asm volatile("s_waitcnt vmcnt(" #N ")" ::: "memory")
#define LGKM0()  do { asm volatile("s_waitcnt lgkmcnt(0)" ::: "memory"); \
                      __builtin_amdgcn_sched_barrier(0); } while (0)

#define MFMA4(mi, a)                                                              \
    acc[mi][0] = __builtin_amdgcn_mfma_f32_16x16x32_bf16(a, b0, acc[mi][0], 0, 0, 0); \
    acc[mi][1] = __builtin_amdgcn_mfma_f32_16x16x32_bf16(a, b1, acc[mi][1], 0, 0, 0); \
    acc[mi][2] = __builtin_amdgcn_mfma_f32_16x16x32_bf16(a, b2, acc[mi][2], 0, 0, 0); \
    acc[mi][3] = __builtin_amdgcn_mfma_f32_16x16x32_bf16(a, b3, acc[mi][3], 0, 0, 0)

#define STAGE_A(TT, NB)                                                           \
    do { const __bf16* g_ = Ag + (TT) * 32;                                       \
         __bf16* l_ = lA + (NB) * 8192;                                           \
         gld_lds16(g_, l_);                                                       \
         gld_lds16(g_ + (size_t)128 * C_DIM, l_ + 4096); } while (0)

#define STAGE_B(TT, NB)                                                           \
    do { const __bf16* g_ = Bg + (TT) * 32;                                       \
         __bf16* l_ = lB + (NB) * 8192;                                           \
         gld_lds16(g_, l_);                                                       \
         gld_lds16(g_ + (size_t)128 * C_DIM, l_ + 4096); } while (0)

#define GBLOCK(BUF, DO_STAGE, TT, DO_VM, VM)                                      \
  { const char* pa = fA + (BUF) * 16384;                                          \
    const char* pb = fB + (BUF) * 16384;                                          \
    bf16x8 af0 = *(const bf16x8*)(pa);                                            \
    bf16x8 af1 = *(const bf16x8*)(pa + 1024);                                     \
    bf16x8 af2 = *(const bf16x8*)(pa + 2048);                                     \
    bf16x8 af3 = *(const bf16x8*)(pa + 3072);                                     \
    bf16x8 b0  = *(const bf16x8*)(pb);                                            \
    bf16x8 b1  = *(const bf16x8*)(pb + 1024);                                     \
    bf16x8 b2  = *(const bf16x8*)(pb + 2048);                                     \
    bf16x8 b3  = *(const bf16x8*)(pb + 3072);                                     \
    if (DO_STAGE) { STAGE_A(TT, ((BUF) + 3) & 3); }                               \
    __builtin_amdgcn_s_barrier();                                                 \
    LGKM0();                                                                      \
    __builtin_amdgcn_s_setprio(1);                                                \
    MFMA4(0, af0); MFMA4(1, af1); MFMA4(2, af2); MFMA4(3, af3);                   \
    __builtin_amdgcn_s_setprio(0);                                                \
    __builtin_amdgcn_s_barrier();                                                 \
    af0 = *(const bf16x8*)(pa + 4096);                                            \
    af1 = *(const bf16x8*)(pa + 5120);                                            \
    af2 = *(const bf16x8*)(pa + 6144);                                            \
    af3 = *(const bf16x8*)(pa + 7168);                                            \
    if (DO_STAGE) { STAGE_B(TT, ((BUF) + 3) & 3); }                               \
    __builtin_amdgcn_s_barrier();                                                 \
    LGKM0();                                                                      \
    __builtin_amdgcn_s_setprio(1);                                                \
    MFMA4(4, af0); MFMA4(5, af1); MFMA4(6, af2); MFMA4(7, af3);                   \
    __builtin_amdgcn_s_setprio(0);                                                \
    if (DO_VM) { VMCNT(VM); }                                                     \
    __builtin_amdgcn_s_barrier();                                                 \
  }

template <bool OUTF32>
__global__ __launch_bounds__(512, 2) void gemm256_bt(
    const __bf16* __restrict__ A, const __bf16* __restrict__ W,
    void* __restrict__ Cout) {
    __shared__ __align__(16) __bf16 sA[4 * 8192];   // 64 KB: 4 tiles, 256x32
    __shared__ __align__(16) __bf16 sB[4 * 8192];   // 64 KB

    const int tid  = threadIdx.x;
    const int lane = tid & 63;
    const int wave = tid >> 6;
    const int wr   = wave >> 2;        // 0..1 -> m offset wr*128
    const int wc   = wave & 3;         // 0..3 -> n offset wc*64

    // XCD swizzle: 256 wgs, 8 XCDs, 32/XCD.  XCD x gets wid x*32..x*32+31 =
    // one n-panel (W rows col0..col0+255, 1MB, L2-resident) x all 32 m-blocks.
    const int bid = blockIdx.x;
    const int wid = (bid & 7) * 32 + (bid >> 3);
    const int m_blk = wid & 31;        // M_DIM/256 == 32
    const int n_blk = wid >> 5;        // C_DIM/256 == 8
    const int row0 = m_blk * 256;
    const int col0 = n_blk * 256;

    // Staging source (inverse-swizzled global col so LDS DMA stays linear):
    // linear LDS slot (unit u = tid>>3, s = tid&7) holds z = s ^ (u&7):
    // row = 2u + (z>>2), colgroup = z&3.
    const int u  = tid >> 3;
    const int z  = (tid & 7) ^ (u & 7);
    const int srow = 2 * u + (z >> 2);            // 0..127 (issue1: +128)
    const int scol = (z & 3) * 8;
    const __bf16* Ag = A + (size_t)(row0 + srow) * C_DIM + scol;
    const __bf16* Bg = W + (size_t)(col0 + srow) * C_DIM + scol;
    __bf16* lA = sA + wave * 512;                 // + buf*8192 + issue*4096
    __bf16* lB = sB + wave * 512;

    // Fragment read base.  Lane reads (row = R0 + (lane&15), q = lane>>4):
    // byte = (row>>1)*128 + ((q + 4*(row&1)) ^ ((row>>1)&7))*16
    //      = R0*64 + lbyte   (R0 multiple of 16 -> lane-constant lbyte).
    const int l15 = lane & 15, l2 = l15 >> 1;
    const int lbyte = l2 * 128 + ((((lane >> 4) + ((lane & 1) << 2)) ^ l2) << 4);
    const char* fA = (const char*)sA + wr * 8192 + lbyte;  // + buf*16384 (+mh*4096 +i*1024)
    const char* fB = (const char*)sB + wc * 4096 + lbyte;  // + buf*16384 (+j*1024)

    f32x4 acc[8][4] = {};

    const int NT = C_DIM / 32;         // 64 K-tiles

    // Prologue: stage tiles 0,1,2 (12 loads); drain tile 0 (leave 8 in flight).
    STAGE_A(0, 0); STAGE_B(0, 0);
    STAGE_A(1, 1); STAGE_B(1, 1);
    STAGE_A(2, 2); STAGE_B(2, 2);
    VMCNT(8);
    __builtin_amdgcn_s_barrier();

#pragma unroll 1
    for (int t = 0; t < NT - 4; t += 4) {
        GBLOCK(0, true, t + 3, true, 8);
        GBLOCK(1, true, t + 4, true, 8);
        GBLOCK(2, true, t + 5, true, 8);
        GBLOCK(3, true, t + 6, true, 8);
    }
    // Peeled tail (tiles NT-4..NT-1): stage last tile, then drain 8 -> 4 -> 0.
    GBLOCK(0, true,  NT - 1, true, 8);
    GBLOCK(1, false, 0,      true, 4);
    GBLOCK(2, false, 0,      true, 0);
    GBLOCK(3, false, 0,      false, 0);

    // Epilogue: D row = (lane>>4)*4 + reg, col = lane&15 (m89-verified).
    const int crow = (lane >> 4) * 4;
#pragma unroll
    for (int mf = 0; mf < 8; ++mf)
#pragma unroll
        for (int jf = 0; jf < 4; ++jf)
#pragma unroll
            for (int r = 0; r < 4; ++r) {
                const int row = row0 + wr * 128 + mf * 16 + crow + r;
                const int col = col0 + wc * 64 + jf * 16 + l15;
                if constexpr (OUTF32) {
                    ((float*)Cout)[(size_t)row * C_DIM + col] = acc[mf][jf][r];
                } else {
                    ((__bf16*)Cout)[(size_t)row * C_DIM + col] = (__bf16)acc[mf][jf][r];
                }
            }
}

// ---------------------------------------------------------------------------
// WKV segmented scan.  State (num, den, mx): stabilized linear recurrence.
// pass1: per (b,c,seg) compute segment aggregate from zero state.
// pass2: per (b,c) sequentially combine aggregates -> incoming state per seg.
// pass3: per (b,c,seg) replay segment from incoming state, emit gated output.
// State layout: [seg][b][c] fp32, coalesced over c.
// ---------------------------------------------------------------------------
__global__ __launch_bounds__(256) void wkv_pass1(
    const __bf16* __restrict__ kbuf, const __bf16* __restrict__ vbuf,
    const float* __restrict__ td,
    float* __restrict__ st_num, float* __restrict__ st_den,
    float* __restrict__ st_m) {
    const int c = blockIdx.x * 256 + threadIdx.x;
    const int b = blockIdx.y;
    const int s = blockIdx.z;
    const size_t base = (size_t)b * T_DIM * C_DIM + (size_t)s * SEGL * C_DIM + c;

    const float w = -__expf(td[c]);
    float num = 0.f, den = 0.f, mx = -1e38f;

    for (int t0 = 0; t0 < SEGL; t0 += 8) {
        float kt[8], vt[8];
#pragma unroll
        for (int j = 0; j < 8; ++j) {
            const size_t idx = base + (size_t)(t0 + j) * C_DIM;
            kt[j] = (float)kbuf[idx];
            vt[j] = (float)vbuf[idx];
        }
#pragma unroll
        for (int j = 0; j < 8; ++j) {
            float ms  = fmaxf(mx + w, kt[j]);
            float e1s = __expf(mx + w - ms);
            float e2s = __expf(kt[j] - ms);
            num = e1s * num + e2s * vt[j];
            den = e1s * den + e2s;
            mx  = ms;
        }
    }
    const size_t sidx = (size_t)s * (B_DIM * C_DIM) + (size_t)b * C_DIM + c;
    st_num[sidx] = num;
    st_den[sidx] = den;
    st_m[sidx]   = mx;
}

__global__ __launch_bounds__(256) void wkv_pass2(
    const float* __restrict__ td,
    float* __restrict__ st_num, float* __restrict__ st_den,
    float* __restrict__ st_m) {
    const int bc = blockIdx.x * 256 + threadIdx.x;   // b*C + c
    const int c  = bc & (C_DIM - 1);
    const float w = -__expf(td[c]);
    const float wL = w * SEGL;

    float num = 0.f, den = 0.f, mx = -1e38f;
    for (int s = 0; s < SEG; ++s) {
        const size_t sidx = (size_t)s * (B_DIM * C_DIM) + bc;
        float na = st_num[sidx], da = st_den[sidx], ma = st_m[sidx];
        // write incoming state for this segment (overwrite aggregate)
        st_num[sidx] = num; st_den[sidx] = den; st_m[sidx] = mx;
        // combine: state <- decay^L(state) + aggregate
        float md = mx + wL;
        float mc = fmaxf(md, ma);
        float e1 = __expf(md - mc);
        float e2 = __expf(ma - mc);
        num = e1 * num + e2 * na;
        den = e1 * den + e2 * da;
        mx  = mc;
    }
}

__global__ __launch_bounds__(256) void wkv_pass3(
    const __bf16* __restrict__ kbuf, const __bf16* __restrict__ vbuf,
    const __bf16* __restrict__ rbuf, const float* __restrict__ td,
    const float* __restrict__ tf,
    const float* __restrict__ st_num, const float* __restrict__ st_den,
    const float* __restrict__ st_m, __bf16* __restrict__ abuf) {
    const int c = blockIdx.x * 256 + threadIdx.x;
    const int b = blockIdx.y;
    const int s = blockIdx.z;
    const size_t base = (size_t)b * T_DIM * C_DIM + (size_t)s * SEGL * C_DIM + c;

    const float w = -__expf(td[c]);
    const float u = tf[c];
    const size_t sidx = (size_t)s * (B_DIM * C_DIM) + (size_t)b * C_DIM + c;
    float num = st_num[sidx], den = st_den[sidx], mx = st_m[sidx];

    for (int t0 = 0; t0 < SEGL; t0 += 8) {
        float kt[8], vt[8], rt[8];
#pragma unroll
        for (int j = 0; j < 8; ++j) {
            const size_t idx = base + (size_t)(t0 + j) * C_DIM;
            kt[j] = (float)kbuf[idx];
            vt[j] = (float)vbuf[idx];
            rt[j] = (float)rbuf[idx];
        }
#pragma unroll
        for (int j = 0; j < 8; ++j) {
            float mo  = fmaxf(mx, kt[j] + u);
            float e1  = __expf(mx - mo);
            float e2  = __expf(kt[j] + u - mo);
            float out = (e1 * num + e2 * vt[j]) / (e1 * den + e2);

            float ms  = fmaxf(mx + w, kt[j]);
            float e1s = __expf(mx + w - ms);
            float e2s = __expf(kt[j] - ms);
            num = e1s * num + e2s * vt[j];
            den = e1s * den + e2s;
            mx  = ms;

            float sr = 1.f / (1.f + __expf(-rt[j]));
            abuf[base + (size_t)(t0 + j) * C_DIM] = (__bf16)(sr * out);
        }
    }
}

// ---------------------------------------------------------------------------
extern "C" void kernel_launch(void* const* d_in, const int* in_sizes, int n_in,
                              void* d_out, int out_size, void* d_ws, size_t ws_size,
                              hipStream_t stream) {
    (void)in_sizes; (void)n_in; (void)out_size; (void)ws_size;
    const float* x  = (const float*)d_in[0];
    const float* td = (const float*)d_in[1];
    const float* tf = (const float*)d_in[2];
    const float* mk = (const float*)d_in[3];
    const float* mv = (const float*)d_in[4];
    const float* mr = (const float*)d_in[5];
    const float* Wk = (const float*)d_in[6];
    const float* Wv = (const float*)d_in[7];
    const float* Wr = (const float*)d_in[8];
    const float* Wo = (const float*)d_in[9];
    float* out = (float*)d_out;

    const size_t WN = (size_t)C_DIM * C_DIM;    // 4,194,304
    const size_t n  = (size_t)M_DIM * C_DIM;    // 16,777,216

    // ws layout (bf16 elements): [Wk|Wv|Wr|Wo bf16][slot0][slot1][slot2][slot3]
    __bf16* Wb  = (__bf16*)d_ws;
    __bf16* Wkb = Wb;
    __bf16* Wvb = Wb + WN;
    __bf16* Wrb = Wb + 2 * WN;
    __bf16* Wob = Wb + 3 * WN;
    __bf16* xk  = Wb + 4 * WN;                  // slot 0
    __bf16* xv  = xk + n;                       // slot 1
    __bf16* xr  = xv + n;                       // slot 2
    __bf16* kb  = xr + n;                       // slot 3
    __bf16* vb  = xk;                           // reuse slot 0 (xk dead)
    __bf16* rb  = xv;                           // reuse slot 1 (xv dead)
    __bf16* ab  = xr;                           // reuse slot 2 (xr dead)

    // WKV state arrays (6.3 MB) live in the Wkb region: Wkb is dead once the
    // k-GEMM completes, and cast_w rewrites it at the start of every launch.
    float* st_num = (float*)d_ws;
    float* st_den = st_num + (size_t)SEG * B_DIM * C_DIM;
    float* st_m   = st_den + (size_t)SEG * B_DIM * C_DIM;

    cast_w_kernel<<<dim3((unsigned)(WN / 4 / 256), 4), 256, 0, stream>>>(
        Wk, Wv, Wr, Wo, Wb);

    mix4_kernel<<<dim3((unsigned)(n / 4 / 256)), 256, 0, stream>>>(
        x, mk, mv, mr, xk, xv, xr);

    dim3 ggrid((M_DIM / 256) * (C_DIM / 256));  // 32 x 8 = 256 blocks (1/CU)
    gemm256_bt<false><<<ggrid, 512, 0, stream>>>(xk, Wkb, kb);
    gemm256_bt<false><<<ggrid, 512, 0, stream>>>(xv, Wvb, vb);
    gemm256_bt<false><<<ggrid, 512, 0, stream>>>(xr, Wrb, rb);

    dim3 wgrid(C_DIM / 256, B_DIM, SEG);        // 8 x 8 x 32 = 2048 blocks
    wkv_pass1<<<wgrid, 256, 0, stream>>>(kb, vb, td, st_num, st_den, st_m);
    wkv_pass2<<<dim3(B_DIM * C_DIM / 256), 256, 0, stream>>>(
        td, st_num, st_den, st_m);
    wkv_pass3<<<wgrid, 256, 0, stream>>>(kb, vb, rb, td, tf,
                                         st_num, st_den, st_m, ab);

    gemm256_bt<true><<<ggrid, 512, 0, stream>>>(ab, Wob, out);
}

// Round 2
// 514.657 us; speedup vs baseline: 1.1371x; 1.0305x over previous
//
#include <hip/hip_runtime.h>
#include <stdint.h>

#define B_DIM 8
#define T_DIM 1024
#define C_DIM 2048
#define M_DIM (B_DIM * T_DIM)   // 8192 rows = B*T
#define SEG   32                // segments for wkv scan
#define SEGL  (T_DIM / SEG)     // 32 steps per segment

typedef __bf16 bf16x8 __attribute__((ext_vector_type(8)));
typedef __bf16 bf16x4 __attribute__((ext_vector_type(4)));
typedef float  f32x4  __attribute__((ext_vector_type(4)));

// ---------------------------------------------------------------------------
// async global -> LDS, 16 bytes per lane (global_load_lds_dwordx4).
// LDS dest is wave-uniform base + lane*16 (m104/m108 semantics).
// ---------------------------------------------------------------------------
__device__ __forceinline__ void gld_lds16(const void* g, void* l) {
    __builtin_amdgcn_global_load_lds((__attribute__((address_space(1))) void*)g,
                                     (__attribute__((address_space(3))) void*)l,
                                     16, 0, 0);
}

// ---------------------------------------------------------------------------
// Downcast the 4 weight matrices fp32 -> bf16.  grid (C*C/1024, 4) x 256.
// ---------------------------------------------------------------------------
__global__ __launch_bounds__(256) void cast_w_kernel(
    const float* __restrict__ w0, const float* __restrict__ w1,
    const float* __restrict__ w2, const float* __restrict__ w3,
    __bf16* __restrict__ dst) {
    const float* srcs[4] = {w0, w1, w2, w3};
    const float* s = srcs[blockIdx.y];
    __bf16* d = dst + (size_t)blockIdx.y * (size_t)C_DIM * C_DIM;
    const size_t i = ((size_t)blockIdx.x * 256 + threadIdx.x) * 4;
    f32x4 v = *(const f32x4*)(s + i);
    bf16x4 o;
#pragma unroll
    for (int j = 0; j < 4; ++j) o[j] = (__bf16)v[j];
    *(bf16x4*)(d + i) = o;
}

// ---------------------------------------------------------------------------
// Time-shift mixing: xk/xv/xr = x*m + shift(x)*(1-m).  fp32 in, bf16 out.
// ---------------------------------------------------------------------------
__global__ __launch_bounds__(256) void mix4_kernel(
    const float* __restrict__ x,
    const float* __restrict__ mk, const float* __restrict__ mv,
    const float* __restrict__ mr,
    __bf16* __restrict__ xk, __bf16* __restrict__ xv, __bf16* __restrict__ xr) {
    const size_t idx = ((size_t)blockIdx.x * 256 + threadIdx.x) * 4;
    const int c = (int)(idx & (C_DIM - 1));
    const int t = (int)((idx >> 11) & (T_DIM - 1));   // C_DIM == 2^11

    f32x4 xc = *(const f32x4*)(x + idx);
    f32x4 sh = {0.f, 0.f, 0.f, 0.f};
    if (t != 0) sh = *(const f32x4*)(x + idx - C_DIM);
    f32x4 k4 = *(const f32x4*)(mk + c);
    f32x4 v4 = *(const f32x4*)(mv + c);
    f32x4 r4 = *(const f32x4*)(mr + c);

    bf16x4 ok, ov, orr;
#pragma unroll
    for (int j = 0; j < 4; ++j) {
        float xx = xc[j], ss = sh[j];
        ok[j]  = (__bf16)(xx * k4[j] + ss * (1.f - k4[j]));
        ov[j]  = (__bf16)(xx * v4[j] + ss * (1.f - v4[j]));
        orr[j] = (__bf16)(xx * r4[j] + ss * (1.f - r4[j]));
    }
    *(bf16x4*)(xk + idx) = ok;
    *(bf16x4*)(xv + idx) = ov;
    *(bf16x4*)(xr + idx) = orr;
}

// ---------------------------------------------------------------------------
// 256x256 bf16 GEMM, B^T input:  Cout[m][n] = sum_k A[m][k] * W[n][k]
//
// In-wave software-pipelined schedule (fixes R1's read/MFMA serialization):
//   - 64-K supertiles, 2-deep LDS double-buffer (2 x 32KB per matrix = 128KB).
//   - 4 phases per supertile, 16 MFMA each.  Phase p ISSUES phase p+1's
//     ds_read_b128 fragments, then waits a COUNTED lgkmcnt(4/8) (drains only
//     the previous phase's reads, leaves the new ones in flight), then runs
//     its MFMA cluster under setprio(1).  LDS reads overlap MFMA within each
//     wave -- no reliance on barrier stagger.
//   - All 8 global_load_lds for supertile s+1 issue at phase 1 of s;
//     vmcnt(0) sits at phase 3 (~2 phases later -> near-free), followed by
//     the mid-barrier (cross-wave DMA visibility) so phase 4 can prefetch
//     the next supertile's phase-1 fragments from the other buffer.
//   - Only 2 barriers per 64-K (mid + boundary).  Race-freedom: the last
//     reads of a buffer are drained by the counted lgkm wait that precedes
//     the boundary barrier that precedes its DMA rewrite; DMA'd data is only
//     read after all-waves vmcnt(0) + mid-barrier.
//   - BK=64 staging = full 128-B rows per supertile (fixes R1's half-line
//     overfetch: FETCH_SIZE 135MB -> ~ideal).
//   - LDS swizzle: row-major [256][64] bf16, 16-B slot s' = g ^ (row&7)
//     (g = k-group).  Inverse applied on the GLOBAL source of the DMA
//     (both-sides-or-neither); every ds_read_b128 hits 64 distinct 16-B
//     slots (measured-0-conflict construction).
//   - grid = 256 blocks = 1/CU; XCD swizzle: each XCD owns one 1MB W-panel.
// ---------------------------------------------------------------------------
#define LGKM(N)  do { asm volatile("s_waitcnt lgkmcnt(" #N ")" ::: "memory"); \
                      __builtin_amdgcn_sched_barrier(0); } while (0)
#define VM0()    asm volatile("s_waitcnt vmcnt(0)" ::: "memory")

#define MF1(mi, jj, AV, BV) \
    acc[mi][jj] = __builtin_amdgcn_mfma_f32_16x16x32_bf16(AV, BV, acc[mi][jj], 0, 0, 0)

#define MFMA16(MB, AA, BB)                                                        \
    __builtin_amdgcn_s_setprio(1);                                                \
    MF1(MB+0,0,AA[0],BB[0]); MF1(MB+0,1,AA[0],BB[1]);                             \
    MF1(MB+0,2,AA[0],BB[2]); MF1(MB+0,3,AA[0],BB[3]);                             \
    MF1(MB+1,0,AA[1],BB[0]); MF1(MB+1,1,AA[1],BB[1]);                             \
    MF1(MB+1,2,AA[1],BB[2]); MF1(MB+1,3,AA[1],BB[3]);                             \
    MF1(MB+2,0,AA[2],BB[0]); MF1(MB+2,1,AA[2],BB[1]);                             \
    MF1(MB+2,2,AA[2],BB[2]); MF1(MB+2,3,AA[2],BB[3]);                             \
    MF1(MB+3,0,AA[3],BB[0]); MF1(MB+3,1,AA[3],BB[1]);                             \
    MF1(MB+3,2,AA[3],BB[2]); MF1(MB+3,3,AA[3],BB[3]);                             \
    __builtin_amdgcn_s_setprio(0)

// stage one 64-K supertile (A and B, 256 rows x 64 k each): 8 gld_lds/thread.
#define STAGE8(KOF, BOE)                                                          \
    do {                                                                          \
        gld_lds16(Ag + (KOF),                       lA + (BOE));                  \
        gld_lds16(Bg + (KOF),                       lB + (BOE));                  \
        gld_lds16(Ag + (KOF) + (size_t)64*C_DIM,    lA + (BOE) + 4096);           \
        gld_lds16(Bg + (KOF) + (size_t)64*C_DIM,    lB + (BOE) + 4096);           \
        gld_lds16(Ag + (KOF) + (size_t)128*C_DIM,   lA + (BOE) + 8192);           \
        gld_lds16(Bg + (KOF) + (size_t)128*C_DIM,   lB + (BOE) + 8192);           \
        gld_lds16(Ag + (KOF) + (size_t)192*C_DIM,   lA + (BOE) + 12288);          \
        gld_lds16(Bg + (KOF) + (size_t)192*C_DIM,   lB + (BOE) + 12288);          \
    } while (0)

template <bool OUTF32>
__global__ __launch_bounds__(512, 2) void gemm256_bt(
    const __bf16* __restrict__ A, const __bf16* __restrict__ W,
    void* __restrict__ Cout) {
    __shared__ __align__(16) __bf16 sA[2 * 16384];   // 64 KB: 2 x [256][64]
    __shared__ __align__(16) __bf16 sB[2 * 16384];   // 64 KB

    const int tid  = threadIdx.x;
    const int lane = tid & 63;
    const int wave = tid >> 6;
    const int wr   = wave >> 2;        // 0..1 -> m offset wr*128
    const int wc   = wave & 3;         // 0..3 -> n offset wc*64

    // XCD swizzle: 256 wgs, 8 XCDs, 32/XCD; XCD x gets one n-panel (1MB W).
    const int bid = blockIdx.x;
    const int wid = (bid & 7) * 32 + (bid >> 3);
    const int m_blk = wid & 31;        // M_DIM/256 == 32
    const int n_blk = wid >> 5;        // C_DIM/256 == 8
    const int row0 = m_blk * 256;
    const int col0 = n_blk * 256;

    // Staging source (inverse-swizzled global k-group so LDS DMA is linear):
    // linear LDS slot (row r = tid>>3, slot s' = tid&7) holds k-group
    // g = s' ^ (r&7).  Issue i advances rows by 64 (swizzle-invariant).
    const int srow = tid >> 3;
    const int sg   = (tid & 7) ^ (srow & 7);
    const __bf16* Ag = A + (size_t)(row0 + srow) * C_DIM + sg * 8;
    const __bf16* Bg = W + (size_t)(col0 + srow) * C_DIM + sg * 8;
    __bf16* lA = sA + wave * 512;      // + buf*16384 + issue*4096 (elements)
    __bf16* lB = sB + wave * 512;

    // Fragment read bases (elements).  Lane (row = R0 + l15, q = lane>>4)
    // reads k-group g = 4*ks + q at slot s' = g ^ (l15&7):
    //   elem = row*64 + s'*8;  ks=1 flips bit2 of s' -> XOR 32 elements.
    const int l15 = lane & 15;
    const int q   = lane >> 4;
    const int sw0 = (q ^ (l15 & 7)) * 8;
    const int aE0 = wr * 8192 + l15 * 64 + sw0;
    const int aE1 = aE0 ^ 32;
    const int bE0 = wc * 4096 + l15 * 64 + sw0;
    const int bE1 = bE0 ^ 32;

    f32x4  acc[8][4] = {};
    bf16x8 a0[4], a1[4], b0f[4], b1f[4];

    // ---- prologue: stage supertile 0 into buf0; preload phase-1 fragments.
    STAGE8(0, 0);
    VM0();
    __builtin_amdgcn_s_barrier();
#pragma unroll
    for (int i = 0; i < 4; ++i) a0[i]  = *(const bf16x8*)(sA + aE0 + i * 1024);
#pragma unroll
    for (int j = 0; j < 4; ++j) b0f[j] = *(const bf16x8*)(sB + bE0 + j * 1024);

    // ---- main loop: supertiles 0..30 (31 iters); supertile 31 peeled.
#pragma unroll 1
    for (int s = 0; s < 31; ++s) {
        const int boe  = (s & 1) << 14;      // current buf (elements)
        const int boe1 = boe ^ 16384;        // next buf

        // ph1 (mh0,ks0): prefetch a1 = A(mh1,ks0); stage s+1; MFMA.
#pragma unroll
        for (int i = 0; i < 4; ++i)
            a1[i] = *(const bf16x8*)(sA + boe + aE0 + 4096 + i * 1024);
        STAGE8((s + 1) * 64, boe1);
        LGKM(4);
        MFMA16(0, a0, b0f);

        // ph2 (mh1,ks0): prefetch a0 = A(mh0,ks1), b1f = B(ks1); MFMA.
#pragma unroll
        for (int i = 0; i < 4; ++i)
            a0[i]  = *(const bf16x8*)(sA + boe + aE1 + i * 1024);
#pragma unroll
        for (int j = 0; j < 4; ++j)
            b1f[j] = *(const bf16x8*)(sB + boe + bE1 + j * 1024);
        LGKM(8);
        MFMA16(4, a1, b0f);

        // ph3 (mh0,ks1): prefetch a1 = A(mh1,ks1); drain DMA; MFMA; mid-bar.
#pragma unroll
        for (int i = 0; i < 4; ++i)
            a1[i] = *(const bf16x8*)(sA + boe + aE1 + 4096 + i * 1024);
        VM0();
        LGKM(4);
        MFMA16(0, a0, b1f);
        __builtin_amdgcn_s_barrier();

        // ph4 (mh1,ks1): prefetch next supertile's ph1 frags from buf1; MFMA.
#pragma unroll
        for (int i = 0; i < 4; ++i)
            a0[i]  = *(const bf16x8*)(sA + boe1 + aE0 + i * 1024);
#pragma unroll
        for (int j = 0; j < 4; ++j)
            b0f[j] = *(const bf16x8*)(sB + boe1 + bE0 + j * 1024);
        LGKM(8);
        MFMA16(4, a1, b1f);
        __builtin_amdgcn_s_barrier();
    }

    // ---- peeled tail: supertile 31 (buf1), no staging, no barriers.
    {
        const int boe = 16384;
#pragma unroll
        for (int i = 0; i < 4; ++i)
            a1[i] = *(const bf16x8*)(sA + boe + aE0 + 4096 + i * 1024);
        LGKM(4);
        MFMA16(0, a0, b0f);
#pragma unroll
        for (int i = 0; i < 4; ++i)
            a0[i]  = *(const bf16x8*)(sA + boe + aE1 + i * 1024);
#pragma unroll
        for (int j = 0; j < 4; ++j)
            b1f[j] = *(const bf16x8*)(sB + boe + bE1 + j * 1024);
        LGKM(8);
        MFMA16(4, a1, b0f);
#pragma unroll
        for (int i = 0; i < 4; ++i)
            a1[i] = *(const bf16x8*)(sA + boe + aE1 + 4096 + i * 1024);
        LGKM(4);
        MFMA16(0, a0, b1f);
        LGKM(0);
        MFMA16(4, a1, b1f);
    }

    // Epilogue: D row = (lane>>4)*4 + reg, col = lane&15 (m89-verified).
    const int crow = (lane >> 4) * 4;
#pragma unroll
    for (int mf = 0; mf < 8; ++mf)
#pragma unroll
        for (int jf = 0; jf < 4; ++jf)
#pragma unroll
            for (int r = 0; r < 4; ++r) {
                const int row = row0 + wr * 128 + mf * 16 + crow + r;
                const int col = col0 + wc * 64 + jf * 16 + l15;
                if constexpr (OUTF32) {
                    ((float*)Cout)[(size_t)row * C_DIM + col] = acc[mf][jf][r];
                } else {
                    ((__bf16*)Cout)[(size_t)row * C_DIM + col] = (__bf16)acc[mf][jf][r];
                }
            }
}

// ---------------------------------------------------------------------------
// WKV segmented scan.  State (num, den, mx): stabilized linear recurrence.
// pass1: per (b,c,seg) compute segment aggregate from zero state.
// pass2: per (b,c) sequentially combine aggregates -> incoming state per seg.
// pass3: per (b,c,seg) replay segment from incoming state, emit gated output.
// State layout: [seg][b][c] fp32, coalesced over c.
// ---------------------------------------------------------------------------
__global__ __launch_bounds__(256) void wkv_pass1(
    const __bf16* __restrict__ kbuf, const __bf16* __restrict__ vbuf,
    const float* __restrict__ td,
    float* __restrict__ st_num, float* __restrict__ st_den,
    float* __restrict__ st_m) {
    const int c = blockIdx.x * 256 + threadIdx.x;
    const int b = blockIdx.y;
    const int s = blockIdx.z;
    const size_t base = (size_t)b * T_DIM * C_DIM + (size_t)s * SEGL * C_DIM + c;

    const float w = -__expf(td[c]);
    float num = 0.f, den = 0.f, mx = -1e38f;

    for (int t0 = 0; t0 < SEGL; t0 += 8) {
        float kt[8], vt[8];
#pragma unroll
        for (int j = 0; j < 8; ++j) {
            const size_t idx = base + (size_t)(t0 + j) * C_DIM;
            kt[j] = (float)kbuf[idx];
            vt[j] = (float)vbuf[idx];
        }
#pragma unroll
        for (int j = 0; j < 8; ++j) {
            float ms  = fmaxf(mx + w, kt[j]);
            float e1s = __expf(mx + w - ms);
            float e2s = __expf(kt[j] - ms);
            num = e1s * num + e2s * vt[j];
            den = e1s * den + e2s;
            mx  = ms;
        }
    }
    const size_t sidx = (size_t)s * (B_DIM * C_DIM) + (size_t)b * C_DIM + c;
    st_num[sidx] = num;
    st_den[sidx] = den;
    st_m[sidx]   = mx;
}

__global__ __launch_bounds__(256) void wkv_pass2(
    const float* __restrict__ td,
    float* __restrict__ st_num, float* __restrict__ st_den,
    float* __restrict__ st_m) {
    const int bc = blockIdx.x * 256 + threadIdx.x;   // b*C + c
    const int c  = bc & (C_DIM - 1);
    const float w = -__expf(td[c]);
    const float wL = w * SEGL;

    float num = 0.f, den = 0.f, mx = -1e38f;
    for (int s = 0; s < SEG; ++s) {
        const size_t sidx = (size_t)s * (B_DIM * C_DIM) + bc;
        float na = st_num[sidx], da = st_den[sidx], ma = st_m[sidx];
        // write incoming state for this segment (overwrite aggregate)
        st_num[sidx] = num; st_den[sidx] = den; st_m[sidx] = mx;
        // combine: state <- decay^L(state) + aggregate
        float md = mx + wL;
        float mc = fmaxf(md, ma);
        float e1 = __expf(md - mc);
        float e2 = __expf(ma - mc);
        num = e1 * num + e2 * na;
        den = e1 * den + e2 * da;
        mx  = mc;
    }
}

__global__ __launch_bounds__(256) void wkv_pass3(
    const __bf16* __restrict__ kbuf, const __bf16* __restrict__ vbuf,
    const __bf16* __restrict__ rbuf, const float* __restrict__ td,
    const float* __restrict__ tf,
    const float* __restrict__ st_num, const float* __restrict__ st_den,
    const float* __restrict__ st_m, __bf16* __restrict__ abuf) {
    const int c = blockIdx.x * 256 + threadIdx.x;
    const int b = blockIdx.y;
    const int s = blockIdx.z;
    const size_t base = (size_t)b * T_DIM * C_DIM + (size_t)s * SEGL * C_DIM + c;

    const float w = -__expf(td[c]);
    const float u = tf[c];
    const size_t sidx = (size_t)s * (B_DIM * C_DIM) + (size_t)b * C_DIM + c;
    float num = st_num[sidx], den = st_den[sidx], mx = st_m[sidx];

    for (int t0 = 0; t0 < SEGL; t0 += 8) {
        float kt[8], vt[8], rt[8];
#pragma unroll
        for (int j = 0; j < 8; ++j) {
            const size_t idx = base + (size_t)(t0 + j) * C_DIM;
            kt[j] = (float)kbuf[idx];
            vt[j] = (float)vbuf[idx];
            rt[j] = (float)rbuf[idx];
        }
#pragma unroll
        for (int j = 0; j < 8; ++j) {
            float mo  = fmaxf(mx, kt[j] + u);
            float e1  = __expf(mx - mo);
            float e2  = __expf(kt[j] + u - mo);
            float out = (e1 * num + e2 * vt[j]) / (e1 * den + e2);

            float ms  = fmaxf(mx + w, kt[j]);
            float e1s = __expf(mx + w - ms);
            float e2s = __expf(kt[j] - ms);
            num = e1s * num + e2s * vt[j];
            den = e1s * den + e2s;
            mx  = ms;

            float sr = 1.f / (1.f + __expf(-rt[j]));
            abuf[base + (size_t)(t0 + j) * C_DIM] = (__bf16)(sr * out);
        }
    }
}

// ---------------------------------------------------------------------------
extern "C" void kernel_launch(void* const* d_in, const int* in_sizes, int n_in,
                              void* d_out, int out_size, void* d_ws, size_t ws_size,
                              hipStream_t stream) {
    (void)in_sizes; (void)n_in; (void)out_size; (void)ws_size;
    const float* x  = (const float*)d_in[0];
    const float* td = (const float*)d_in[1];
    const float* tf = (const float*)d_in[2];
    const float* mk = (const float*)d_in[3];
    const float* mv = (const float*)d_in[4];
    const float* mr = (const float*)d_in[5];
    const float* Wk = (const float*)d_in[6];
    const float* Wv = (const float*)d_in[7];
    const float* Wr = (const float*)d_in[8];
    const float* Wo = (const float*)d_in[9];
    float* out = (float*)d_out;

    const size_t WN = (size_t)C_DIM * C_DIM;    // 4,194,304
    const size_t n  = (size_t)M_DIM * C_DIM;    // 16,777,216

    // ws layout (bf16 elements): [Wk|Wv|Wr|Wo bf16][slot0][slot1][slot2][slot3]
    __bf16* Wb  = (__bf16*)d_ws;
    __bf16* Wkb = Wb;
    __bf16* Wvb = Wb + WN;
    __bf16* Wrb = Wb + 2 * WN;
    __bf16* Wob = Wb + 3 * WN;
    __bf16* xk  = Wb + 4 * WN;                  // slot 0
    __bf16* xv  = xk + n;                       // slot 1
    __bf16* xr  = xv + n;                       // slot 2
    __bf16* kb  = xr + n;                       // slot 3
    __bf16* vb  = xk;                           // reuse slot 0 (xk dead)
    __bf16* rb  = xv;                           // reuse slot 1 (xv dead)
    __bf16* ab  = xr;                           // reuse slot 2 (xr dead)

    // WKV state arrays (6.3 MB) live in the Wkb region: Wkb is dead once the
    // k-GEMM completes, and cast_w rewrites it at the start of every launch.
    float* st_num = (float*)d_ws;
    float* st_den = st_num + (size_t)SEG * B_DIM * C_DIM;
    float* st_m   = st_den + (size_t)SEG * B_DIM * C_DIM;

    cast_w_kernel<<<dim3((unsigned)(WN / 4 / 256), 4), 256, 0, stream>>>(
        Wk, Wv, Wr, Wo, Wb);

    mix4_kernel<<<dim3((unsigned)(n / 4 / 256)), 256, 0, stream>>>(
        x, mk, mv, mr, xk, xv, xr);

    dim3 ggrid((M_DIM / 256) * (C_DIM / 256));  // 32 x 8 = 256 blocks (1/CU)
    gemm256_bt<false><<<ggrid, 512, 0, stream>>>(xk, Wkb, kb);
    gemm256_bt<false><<<ggrid, 512, 0, stream>>>(xv, Wvb, vb);
    gemm256_bt<false><<<ggrid, 512, 0, stream>>>(xr, Wrb, rb);

    dim3 wgrid(C_DIM / 256, B_DIM, SEG);        // 8 x 8 x 32 = 2048 blocks
    wkv_pass1<<<wgrid, 256, 0, stream>>>(kb, vb, td, st_num, st_den, st_m);
    wkv_pass2<<<dim3(B_DIM * C_DIM / 256), 256, 0, stream>>>(
        td, st_num, st_den, st_m);
    wkv_pass3<<<wgrid, 256, 0, stream>>>(kb, vb, rb, td, tf,
                                         st_num, st_den, st_m, ab);

    gemm256_bt<true><<<ggrid, 512, 0, stream>>>(ab, Wob, out);
}